// Round 2
// baseline (647.442 us; speedup 1.0000x reference)
//
#include <hip/hip_runtime.h>
#include <hip/hip_bf16.h>
#include <math.h>

#define TOK 4096
#define HD 1024
#define FD 4096
#define NE 8

typedef __attribute__((ext_vector_type(4))) float f32x4;
typedef __attribute__((ext_vector_type(8))) short s16x8;
typedef __attribute__((ext_vector_type(4))) unsigned int u32x4;

__device__ __forceinline__ unsigned short f2bf(float f) {
    union { float f; unsigned u; } v; v.f = f;
    unsigned r = v.u + 0x7FFFu + ((v.u >> 16) & 1u);   // RNE
    return (unsigned short)(r >> 16);
}

// v_cvt_pk_bf16_f32: lo16 = bf16(a), hi16 = bf16(b), RNE
__device__ __forceinline__ unsigned cvt2(float a, float b) {
    unsigned r;
    asm("v_cvt_pk_bf16_f32 %0, %1, %2" : "=v"(r) : "v"(a), "v"(b));
    return r;
}

// ---------------- router: sigmoid(x@Wr+br), top-1, compact lists, cast x->bf16
__global__ void router_kernel(const float* __restrict__ x, const float* __restrict__ Wr,
                              const float* __restrict__ br, int* __restrict__ counts,
                              int* __restrict__ tlist, float* __restrict__ mprob,
                              unsigned short* __restrict__ xb) {
    const int lane = threadIdx.x & 63;
    const int t = blockIdx.x * 4 + (threadIdx.x >> 6);
    const float* xr = x + (size_t)t * HD;
    unsigned short* xbr = xb + (size_t)t * HD;
    float acc[NE];
#pragma unroll
    for (int e = 0; e < NE; ++e) acc[e] = 0.f;
    for (int h = lane; h < HD; h += 64) {
        float xv = xr[h];
        xbr[h] = f2bf(xv);                          // coalesced bf16 cast-out
        f32x4 w0 = *(const f32x4*)(Wr + h * NE);
        f32x4 w1 = *(const f32x4*)(Wr + h * NE + 4);
        acc[0] += xv * w0.x; acc[1] += xv * w0.y; acc[2] += xv * w0.z; acc[3] += xv * w0.w;
        acc[4] += xv * w1.x; acc[5] += xv * w1.y; acc[6] += xv * w1.z; acc[7] += xv * w1.w;
    }
#pragma unroll
    for (int off = 32; off >= 1; off >>= 1)
#pragma unroll
        for (int e = 0; e < NE; ++e) acc[e] += __shfl_down(acc[e], off, 64);
    if (lane == 0) {
        float best = -1.f; int bi = 0;
#pragma unroll
        for (int e = 0; e < NE; ++e) {
            float r = 1.f / (1.f + expf(-(acc[e] + br[e])));
            if (r > best) { best = r; bi = e; }   // strict > keeps first index on tie
        }
        mprob[t] = best;
        int pos = atomicAdd(&counts[bi], 1);
        tlist[bi * TOK + pos] = t;
    }
}

// ---------------- gathered expert GEMM: A direct-global, B reg-staged+cvt ------
// A fragments: 16-B k-contiguous loads per (token-row, quad) straight from
// global (L1/L2-hot tile) -> no A LDS, no DMA, no vmcnt drain.
// B: thread (gg=tid&7 k-group, cg=tid>>3 n-quad) loads 8 x f32x4 of the native
// [K][N] fp32 weights (128-B contiguous chunks per row), cvt_pk -> bf16 in reg,
// ds_write_b128 into the XOR-swizzled Bl[n][k] layout. Both the write pattern
// (class=(gg+4cg+i)&7: gg spans 0..7 within every 16-lane group) and the
// compute read pattern are at the wave64-b128 conflict-free minimum.
// Bl is TRIPLE-buffered -> exactly ONE raw s_barrier (lgkmcnt-only) per K-step:
// window between barrier(t) and barrier(t+1) touches Bl[t%3] (read) and
// Bl[(t+2)%3] (write) -- distinct mod 3. B raw loads issued one full iteration
// ahead; no vmcnt(0) anywhere in the loop.
// LDS 48 KB + VGPR<=168 -> 3 blocks/CU (12 waves).
template<int K, bool FC1, int KSPLIT>
__global__ __launch_bounds__(256, 3)
void expert_gemm(const unsigned short* __restrict__ Asrc, const float* __restrict__ Wsrc,
                 const int* __restrict__ counts, const int* __restrict__ tlist,
                 const float* __restrict__ mprob,
                 unsigned short* __restrict__ inter, float* __restrict__ out) {
    constexpr int NDIM = FC1 ? FD : HD;
    constexpr int KC = K / KSPLIT;
    constexpr int NT = KC / 64;
    const int e  = (KSPLIT == 1) ? (int)blockIdx.z : ((int)blockIdx.z & (NE - 1));
    const int ks = (KSPLIT == 1) ? 0 : ((int)blockIdx.z >> 3);
    const int kbase = ks * KC;
    const int cnt = counts[e];
    const int m0 = blockIdx.y * 128;
    if (m0 >= cnt) return;
    const int n0 = blockIdx.x * 128;

    __shared__ unsigned short Bl[3][128 * 64];

    const int tid = threadIdx.x;
    const int lane = tid & 63;
    const int wave = tid >> 6;
    const int wrow = (wave >> 1) << 6;
    const int wcol = (wave & 1) << 6;
    const int lm = lane & 15, quad = lane >> 4;

    // A fragment pointers (direct-from-global); OOB rows clamp to token 0,
    // their outputs are discarded in the epilogue.
    const unsigned short* aPtr[4];
#pragma unroll
    for (int mt = 0; mt < 4; ++mt) {
        int m = m0 + wrow + (mt << 4) + lm;
        int tk = (m < cnt) ? tlist[e * TOK + m] : 0;
        aPtr[mt] = Asrc + (size_t)tk * K + kbase + (quad << 3);
    }

    const int gg = tid & 7;    // k-group (8 rows)
    const int cg = tid >> 3;   // n-quad (4 cols) 0..31
    const float* bPtr = Wsrc + ((size_t)e * K + kbase + (gg << 3)) * NDIM + n0 + (cg << 2);

    f32x4 breg[8];
    auto loadB = [&]() {
#pragma unroll
        for (int j = 0; j < 8; ++j) breg[j] = *(const f32x4*)(bPtr + (size_t)j * NDIM);
        bPtr += (size_t)64 * NDIM;
    };
    auto cvtB = [&](unsigned short* __restrict__ dst) {
#pragma unroll
        for (int i = 0; i < 4; ++i) {          // static indices only (rule 20)
            int n = (cg << 2) + i;
            u32x4 q;
            q.x = cvt2(breg[0][i], breg[1][i]);
            q.y = cvt2(breg[2][i], breg[3][i]);
            q.z = cvt2(breg[4][i], breg[5][i]);
            q.w = cvt2(breg[6][i], breg[7][i]);
            *(u32x4*)&dst[(n << 6) + (((gg + n) & 7) << 3)] = q;
        }
    };

    f32x4 acc[4][4] = {};

    loadB();             // RAW(0)
    cvtB(&Bl[0][0]);     // Bl[0] = B(0)
    loadB();             // RAW(1) in flight

    int bufC = 0;
    for (int tt = 0; tt < NT; ++tt) {
        int bufW = bufC + 1; if (bufW == 3) bufW = 0;
        if (tt + 1 < NT) {
            cvtB(&Bl[bufW][0]);            // consumes RAW(tt+1)
            if (tt + 2 < NT) loadB();      // RAW(tt+2) flies under compute(tt)
        }
        asm volatile("s_waitcnt lgkmcnt(0)\n\ts_barrier" ::: "memory");
        const unsigned short* blc = &Bl[bufC][0];
#pragma unroll
        for (int kt = 0; kt < 2; ++kt) {
            s16x8 af[4], bf[4];
#pragma unroll
            for (int mt = 0; mt < 4; ++mt)
                af[mt] = *(const s16x8*)(aPtr[mt] + (kt << 5));
#pragma unroll
            for (int nt = 0; nt < 4; ++nt) {
                int n = wcol + (nt << 4) + lm;
                int gk = (kt << 2) + quad;
                bf[nt] = *(const s16x8*)&blc[(n << 6) + (((gk + n) & 7) << 3)];
            }
#pragma unroll
            for (int mt = 0; mt < 4; ++mt)
#pragma unroll
                for (int nt = 0; nt < 4; ++nt)
                    acc[mt][nt] = __builtin_amdgcn_mfma_f32_16x16x32_bf16(
                        af[mt], bf[nt], acc[mt][nt], 0, 0, 0);
        }
#pragma unroll
        for (int mt = 0; mt < 4; ++mt) aPtr[mt] += 64;
        bufC = bufW;
    }

    // ---- epilogue: C/D layout col=lane&15, row=quad*4+reg. tlist/mprob reloads
    // are broadcast dword loads (L1-hot) -- cheaper than LDS + prologue barrier.
#pragma unroll
    for (int mt = 0; mt < 4; ++mt) {
#pragma unroll
        for (int r = 0; r < 4; ++r) {
            int row = wrow + (mt << 4) + (quad << 2) + r;
            if (m0 + row >= cnt) continue;
            int tk = tlist[e * TOK + m0 + row];
            int colb = n0 + wcol + lm;
            if constexpr (FC1) {
#pragma unroll
                for (int nt = 0; nt < 4; ++nt) {
                    float v = acc[mt][nt][r];
                    float g = 0.5f * v * (1.f + erff(v * 0.70710678f));  // exact gelu
                    inter[(size_t)tk * FD + colb + (nt << 4)] = f2bf(g);
                }
            } else {
                float p = mprob[tk];
#pragma unroll
                for (int nt = 0; nt < 4; ++nt)
                    atomicAdd(&out[(size_t)tk * HD + colb + (nt << 4)], acc[mt][nt][r] * p);
            }
        }
    }
}

extern "C" void kernel_launch(void* const* d_in, const int* in_sizes, int n_in,
                              void* d_out, int out_size, void* d_ws, size_t ws_size,
                              hipStream_t stream) {
    const float* x  = (const float*)d_in[0];
    const float* Wr = (const float*)d_in[1];
    const float* br = (const float*)d_in[2];
    const float* W1 = (const float*)d_in[3];
    const float* W2 = (const float*)d_in[4];
    float* out = (float*)d_out;

    char* ws = (char*)d_ws;
    int* counts           = (int*)ws;                           // 32 B (pad 256)
    float* mprob          = (float*)(ws + 256);                 // 16 KB
    int* tlist            = (int*)(ws + 16640);                 // 128 KB
    unsigned short* xb    = (unsigned short*)(ws + 147712);     // TOK*HD bf16, 8 MB
    unsigned short* inter = (unsigned short*)(ws + 8536320);    // TOK*FD bf16, 32 MB

    hipMemsetAsync(counts, 0, NE * sizeof(int), stream);
    hipMemsetAsync(out, 0, (size_t)out_size * sizeof(float), stream);  // split-K accumulates
    router_kernel<<<TOK / 4, 256, 0, stream>>>(x, Wr, br, counts, tlist, mprob, xb);

    // fc1: gelu(x @ W1) -> inter (bf16).  x = N-blocks (all live -> XCD spread)
    expert_gemm<HD, true, 1><<<dim3(FD / 128, TOK / 128, NE), 256, 0, stream>>>(
        xb, W1, counts, tlist, mprob, inter, nullptr);

    // fc2: (inter @ W2) * max_prob -> out (fp32), split-K=4, atomic accumulate
    expert_gemm<FD, false, 4><<<dim3(HD / 128, TOK / 128, NE * 4), 256, 0, stream>>>(
        inter, W2, counts, tlist, mprob, nullptr, out);
}

// Round 3
// 546.515 us; speedup vs baseline: 1.1847x; 1.1847x over previous
//
#include <hip/hip_runtime.h>
#include <hip/hip_bf16.h>
#include <math.h>

#define TOK 4096
#define HD 1024
#define FD 4096
#define NE 8

typedef __attribute__((ext_vector_type(4))) float f32x4;
typedef __attribute__((ext_vector_type(8))) short s16x8;
typedef __attribute__((ext_vector_type(4))) unsigned int u32x4;

typedef const __attribute__((address_space(1))) void g_void;
typedef __attribute__((address_space(3))) void lds_void;

__device__ __forceinline__ unsigned short f2bf(float f) {
    union { float f; unsigned u; } v; v.f = f;
    unsigned r = v.u + 0x7FFFu + ((v.u >> 16) & 1u);   // RNE
    return (unsigned short)(r >> 16);
}

// v_cvt_pk_bf16_f32: lo16 = bf16(a), hi16 = bf16(b), RNE
__device__ __forceinline__ unsigned cvt2(float a, float b) {
    unsigned r;
    asm("v_cvt_pk_bf16_f32 %0, %1, %2" : "=v"(r) : "v"(a), "v"(b));
    return r;
}

// ---------------- router: sigmoid(x@Wr+br), top-1, compact lists, cast x->bf16
__global__ void router_kernel(const float* __restrict__ x, const float* __restrict__ Wr,
                              const float* __restrict__ br, int* __restrict__ counts,
                              int* __restrict__ tlist, float* __restrict__ mprob,
                              unsigned short* __restrict__ xb) {
    const int lane = threadIdx.x & 63;
    const int t = blockIdx.x * 4 + (threadIdx.x >> 6);
    const float* xr = x + (size_t)t * HD;
    unsigned short* xbr = xb + (size_t)t * HD;
    float acc[NE];
#pragma unroll
    for (int e = 0; e < NE; ++e) acc[e] = 0.f;
    for (int h = lane; h < HD; h += 64) {
        float xv = xr[h];
        xbr[h] = f2bf(xv);                          // coalesced bf16 cast-out
        f32x4 w0 = *(const f32x4*)(Wr + h * NE);
        f32x4 w1 = *(const f32x4*)(Wr + h * NE + 4);
        acc[0] += xv * w0.x; acc[1] += xv * w0.y; acc[2] += xv * w0.z; acc[3] += xv * w0.w;
        acc[4] += xv * w1.x; acc[5] += xv * w1.y; acc[6] += xv * w1.z; acc[7] += xv * w1.w;
    }
#pragma unroll
    for (int off = 32; off >= 1; off >>= 1)
#pragma unroll
        for (int e = 0; e < NE; ++e) acc[e] += __shfl_down(acc[e], off, 64);
    if (lane == 0) {
        float best = -1.f; int bi = 0;
#pragma unroll
        for (int e = 0; e < NE; ++e) {
            float r = 1.f / (1.f + expf(-(acc[e] + br[e])));
            if (r > best) { best = r; bi = e; }   // strict > keeps first index on tie
        }
        mprob[t] = best;
        int pos = atomicAdd(&counts[bi], 1);
        tlist[bi * TOK + pos] = t;
    }
}

// ---------------- fast transpose+cast: src [E][K][N] fp32 -> dst [E][N][K] bf16
// Per block: 64k x 128n tile. Phase1: thread (gg=tid&7, cg=tid>>3) loads 8 rows
// of f32x4 (coalesced 512B per (row,j)), cvt_pk to bf16, ds_write_b128 into the
// XOR-swizzled [n][slot] layout (slot (gg+n)&7 holds k-group gg) -- the exact
// pattern measured at 0 bank conflicts in round 2's cvtB. Phase2: thread
// (n=tid>>1, half=tid&1) reads 4 b128 chunks (bank classes all distinct per
// 8-lane group) and stores 64B contiguous to dst[n][k].
template<int K, int N>
__global__ __launch_bounds__(256)
void transpose_cast(const float* __restrict__ src, unsigned short* __restrict__ dst) {
    __shared__ unsigned short T[128 * 64];   // 16 KB
    const int e  = blockIdx.z;
    const int n0 = blockIdx.x * 128;
    const int k0 = blockIdx.y * 64;
    const int tid = threadIdx.x;
    {
        const int gg = tid & 7;        // k-group (8 rows)
        const int cg = tid >> 3;       // n-quad (4 cols) 0..31
        const float* sp = src + ((size_t)e * K + k0 + gg * 8) * N + n0 + (cg << 2);
        f32x4 v[8];
#pragma unroll
        for (int j = 0; j < 8; ++j) v[j] = *(const f32x4*)(sp + (size_t)j * N);
#pragma unroll
        for (int i = 0; i < 4; ++i) {
            int n = (cg << 2) + i;
            u32x4 q;
            q.x = cvt2(v[0][i], v[1][i]);
            q.y = cvt2(v[2][i], v[3][i]);
            q.z = cvt2(v[4][i], v[5][i]);
            q.w = cvt2(v[6][i], v[7][i]);
            *(u32x4*)&T[(n << 6) + (((gg + n) & 7) << 3)] = q;
        }
    }
    __syncthreads();
    {
        const int n = tid >> 1;
        const int half = tid & 1;
        unsigned short* op = dst + ((size_t)e * N + n0 + n) * K + k0 + half * 32;
#pragma unroll
        for (int j = 0; j < 4; ++j) {
            int kg = half * 4 + j;
            s16x8 c = *(const s16x8*)&T[(n << 6) + (((kg + n) & 7) << 3)];
            *(s16x8*)(op + j * 8) = c;
        }
    }
}

// ---------------- gathered expert GEMM (128x128 tile, 16x16x32 bf16 MFMA) ------
// Round-0 structure (all-bf16, global_load_lds staging, swizzled-global LDS
// layout measured at 0 bank conflicts) upgraded with the T3-minimum pipeline:
// A and B tiles DOUBLE-buffered; per K-step:
//   s_waitcnt vmcnt(0)      -- my DMA(t) landed
//   s_barrier (raw)         -- everyone's DMA(t) landed, everyone done compute(t-1)
//   issue DMA(t+1) -> buf^1 -- safe (no wave still reads buf^1); flies under compute
//   compute(t) from buf     -- 8 ds_read_b128 + 32 MFMA
// One barrier per iter, no drain window: the 8 in-flight loads have a full
// compute phase (~200+ cyc) to land. LDS 64 KB -> 2 blocks/CU.
template<int K, bool FC1, int KSPLIT>
__global__ __launch_bounds__(256, 2)
void expert_gemm(const unsigned short* __restrict__ Asrc, const unsigned short* __restrict__ Wt,
                 const int* __restrict__ counts, const int* __restrict__ tlist,
                 const float* __restrict__ mprob,
                 unsigned short* __restrict__ inter, float* __restrict__ out) {
    constexpr int NDIM = FC1 ? FD : HD;
    constexpr int KC = K / KSPLIT;
    constexpr int NT = KC / 64;
    const int e  = (KSPLIT == 1) ? (int)blockIdx.z : ((int)blockIdx.z & (NE - 1));
    const int ks = (KSPLIT == 1) ? 0 : ((int)blockIdx.z >> 3);
    const int kbase = ks * KC;
    const int cnt = counts[e];
    const int m0 = blockIdx.y * 128;
    if (m0 >= cnt) return;
    const int n0 = blockIdx.x * 128;

    __shared__ unsigned short Al[2][128 * 64];
    __shared__ unsigned short Bl[2][128 * 64];

    const int tid = threadIdx.x;
    const int lane = tid & 63;
    const int wave = tid >> 6;

    // swizzled-global staging: lane (lr,g) feeds LDS slot g of row r; the slot
    // holds k-group kg=(g-r)&7 so fragment reads are conflict-free.
    const unsigned short* aptr[4];
    const unsigned short* bptr[4];
    {
        int lr = lane >> 3, g = lane & 7;
#pragma unroll
        for (int it = 0; it < 4; ++it) {
            int r = wave * 32 + it * 8 + lr;
            int kg = (g - r) & 7;
            int m = m0 + r;
            int tk = (m < cnt) ? tlist[e * TOK + m] : 0;  // clamp: row discarded in epilogue
            aptr[it] = Asrc + (size_t)tk * K + kbase + kg * 8;
            bptr[it] = Wt + ((size_t)e * NDIM + n0 + r) * K + kbase + kg * 8;
        }
    }

    const int wrow = (wave >> 1) << 6;
    const int wcol = (wave & 1) << 6;
    const int lm = lane & 15, quad = lane >> 4;

    f32x4 acc[4][4] = {};

    // DMA(0)
#pragma unroll
    for (int it = 0; it < 4; ++it) {
        __builtin_amdgcn_global_load_lds((g_void*)aptr[it],
            (lds_void*)&Al[0][wave * 2048 + it * 512], 16, 0, 0);
        __builtin_amdgcn_global_load_lds((g_void*)bptr[it],
            (lds_void*)&Bl[0][wave * 2048 + it * 512], 16, 0, 0);
        aptr[it] += 64; bptr[it] += 64;
    }

    for (int t = 0; t < NT; ++t) {
        const int buf = t & 1;
        asm volatile("s_waitcnt vmcnt(0)" ::: "memory");   // my DMA(t) landed
        __builtin_amdgcn_s_barrier();                      // everyone's landed + compute(t-1) done
        if (t + 1 < NT) {                                  // prefetch flies under compute(t)
#pragma unroll
            for (int it = 0; it < 4; ++it) {
                __builtin_amdgcn_global_load_lds((g_void*)aptr[it],
                    (lds_void*)&Al[buf ^ 1][wave * 2048 + it * 512], 16, 0, 0);
                __builtin_amdgcn_global_load_lds((g_void*)bptr[it],
                    (lds_void*)&Bl[buf ^ 1][wave * 2048 + it * 512], 16, 0, 0);
                aptr[it] += 64; bptr[it] += 64;
            }
            __builtin_amdgcn_sched_barrier(0);             // keep DMA issue ahead of frag reads
        }
        const unsigned short* Ab = &Al[buf][0];
        const unsigned short* Bb = &Bl[buf][0];
#pragma unroll
        for (int kt = 0; kt < 2; ++kt) {
            s16x8 af[4], bf[4];
            int gk = (kt << 2) + quad;
#pragma unroll
            for (int mt = 0; mt < 4; ++mt) {
                int m = wrow + (mt << 4) + lm;
                af[mt] = *(const s16x8*)&Ab[(m << 6) + (((gk + m) & 7) << 3)];
            }
#pragma unroll
            for (int nt = 0; nt < 4; ++nt) {
                int n = wcol + (nt << 4) + lm;
                bf[nt] = *(const s16x8*)&Bb[(n << 6) + (((gk + n) & 7) << 3)];
            }
#pragma unroll
            for (int mt = 0; mt < 4; ++mt)
#pragma unroll
                for (int nt = 0; nt < 4; ++nt)
                    acc[mt][nt] = __builtin_amdgcn_mfma_f32_16x16x32_bf16(
                        af[mt], bf[nt], acc[mt][nt], 0, 0, 0);
        }
    }

    // ---- epilogue: C/D layout col=lane&15, row=quad*4+reg
#pragma unroll
    for (int mt = 0; mt < 4; ++mt) {
#pragma unroll
        for (int r = 0; r < 4; ++r) {
            int row = wrow + (mt << 4) + (quad << 2) + r;
            if (m0 + row >= cnt) continue;
            int tk = tlist[e * TOK + m0 + row];
            int colb = n0 + wcol + lm;
            if constexpr (FC1) {
#pragma unroll
                for (int nt = 0; nt < 4; ++nt) {
                    float v = acc[mt][nt][r];
                    float g = 0.5f * v * (1.f + erff(v * 0.70710678f));  // exact gelu
                    inter[(size_t)tk * FD + colb + (nt << 4)] = f2bf(g);
                }
            } else {
                float p = mprob[tk];
#pragma unroll
                for (int nt = 0; nt < 4; ++nt)
                    atomicAdd(&out[(size_t)tk * HD + colb + (nt << 4)], acc[mt][nt][r] * p);
            }
        }
    }
}

extern "C" void kernel_launch(void* const* d_in, const int* in_sizes, int n_in,
                              void* d_out, int out_size, void* d_ws, size_t ws_size,
                              hipStream_t stream) {
    const float* x  = (const float*)d_in[0];
    const float* Wr = (const float*)d_in[1];
    const float* br = (const float*)d_in[2];
    const float* W1 = (const float*)d_in[3];
    const float* W2 = (const float*)d_in[4];
    float* out = (float*)d_out;

    char* ws = (char*)d_ws;
    int* counts           = (int*)ws;                           // 32 B (pad 256)
    float* mprob          = (float*)(ws + 256);                 // 16 KB
    int* tlist            = (int*)(ws + 16640);                 // 128 KB
    unsigned short* xb    = (unsigned short*)(ws + 147712);     // TOK*HD bf16, 8 MB
    unsigned short* inter = (unsigned short*)(ws + 8536320);    // TOK*FD bf16, 32 MB
    unsigned short* Wt    = (unsigned short*)(ws + 42090752);   // 8*4096*1024 bf16, 64 MB (shared W1t/W2t)

    hipMemsetAsync(counts, 0, NE * sizeof(int), stream);
    hipMemsetAsync(out, 0, (size_t)out_size * sizeof(float), stream);  // split-K accumulates
    router_kernel<<<TOK / 4, 256, 0, stream>>>(x, Wr, br, counts, tlist, mprob, xb);

    // W1 [E][HD][FD] -> Wt [E][FD][HD] bf16
    transpose_cast<HD, FD><<<dim3(FD / 128, HD / 64, NE), 256, 0, stream>>>(W1, Wt);
    // fc1: gelu(x @ W1) -> inter (bf16).  x = N-blocks (all live -> XCD spread)
    expert_gemm<HD, true, 1><<<dim3(FD / 128, TOK / 128, NE), 256, 0, stream>>>(
        xb, Wt, counts, tlist, mprob, inter, nullptr);

    // W2 [E][FD][HD] -> Wt [E][HD][FD] bf16 (reuse buffer; stream serializes)
    transpose_cast<FD, HD><<<dim3(HD / 128, FD / 64, NE), 256, 0, stream>>>(W2, Wt);
    // fc2: (inter @ W2) * max_prob -> out (fp32), split-K=4, atomic accumulate
    expert_gemm<FD, false, 4><<<dim3(HD / 128, TOK / 128, NE * 4), 256, 0, stream>>>(
        inter, Wt, counts, tlist, mprob, nullptr, out);
}